// Round 2
// baseline (1515.088 us; speedup 1.0000x reference)
//
#include <hip/hip_runtime.h>

// C[M x N] = A[M x K] @ W[K x N]  (fp32). Block: 256 threads, 64 rows x 128 cols.
// Per-thread 8x4. A staged in LDS; W streamed from global (L1/L2 resident).
template<int K, bool ACC, bool RELU, bool BIAS>
__global__ __launch_bounds__(256) void gemm_k(
    const float* __restrict__ A, const float* __restrict__ W,
    const float* __restrict__ bias, float* __restrict__ C,
    int M, int N)
{
    __shared__ float As[64 * K];
    const int tid = threadIdx.x;
    const int m0 = blockIdx.x * 64;

    // stage A tile (64 x K fp32) with float4 loads, row-guarded
    const int AV = 64 * K / 4;
    float4* As4 = (float4*)As;
    for (int i = tid; i < AV; i += 256) {
        int row = i / (K / 4), c4 = i % (K / 4);
        int gr = m0 + row;
        float4 v = make_float4(0.f, 0.f, 0.f, 0.f);
        if (gr < M) v = ((const float4*)(A + (size_t)gr * K))[c4];
        As4[i] = v;
    }
    __syncthreads();

    const int tx = tid & 31, ty = tid >> 5;
    const int c0 = blockIdx.y * 128 + tx * 4;

    float acc[8][4];
#pragma unroll
    for (int r = 0; r < 8; r++) { acc[r][0]=0.f; acc[r][1]=0.f; acc[r][2]=0.f; acc[r][3]=0.f; }

    for (int k = 0; k < K; k += 4) {
        float bv[4][4];
#pragma unroll
        for (int kk = 0; kk < 4; kk++) {
            float4 w = *(const float4*)(W + (size_t)(k + kk) * N + c0);
            bv[kk][0] = w.x; bv[kk][1] = w.y; bv[kk][2] = w.z; bv[kk][3] = w.w;
        }
#pragma unroll
        for (int r = 0; r < 8; r++) {
            float4 av = *(const float4*)(&As[(ty * 8 + r) * K + k]);
#pragma unroll
            for (int c = 0; c < 4; c++) {
                acc[r][c] = fmaf(av.x, bv[0][c], acc[r][c]);
                acc[r][c] = fmaf(av.y, bv[1][c], acc[r][c]);
                acc[r][c] = fmaf(av.z, bv[2][c], acc[r][c]);
                acc[r][c] = fmaf(av.w, bv[3][c], acc[r][c]);
            }
        }
    }

    float bb[4] = {0.f, 0.f, 0.f, 0.f};
    if (BIAS) {
        float4 b4 = *(const float4*)(bias + c0);
        bb[0] = b4.x; bb[1] = b4.y; bb[2] = b4.z; bb[3] = b4.w;
    }

#pragma unroll
    for (int r = 0; r < 8; r++) {
        int gr = m0 + ty * 8 + r;
        if (gr >= M) continue;
        size_t base = (size_t)gr * N + c0;
        if (ACC) {
            float4 c4 = *(float4*)(C + base);
            c4.x += acc[r][0]; c4.y += acc[r][1]; c4.z += acc[r][2]; c4.w += acc[r][3];
            *(float4*)(C + base) = c4;
        } else {
            float v0 = acc[r][0] + bb[0], v1 = acc[r][1] + bb[1];
            float v2 = acc[r][2] + bb[2], v3 = acc[r][3] + bb[3];
            if (RELU) {
                v0 = fmaxf(v0, 0.f); v1 = fmaxf(v1, 0.f);
                v2 = fmaxf(v2, 0.f); v3 = fmaxf(v3, 0.f);
            }
            *(float4*)(C + base) = make_float4(v0, v1, v2, v3);
        }
    }
}

// Edge scatter: msg[dst[e]] += X[src[e]]  (fp32 atomics; 64 lanes/edge x 2 floats)
__global__ __launch_bounds__(256) void scat_k(
    const float* __restrict__ X, const int* __restrict__ src,
    const int* __restrict__ dst, float* __restrict__ msg, int E)
{
    long long gid = (long long)blockIdx.x * 256 + threadIdx.x;
    int e = (int)(gid >> 6);
    if (e >= E) return;
    int c = ((int)gid & 63) * 2;
    int s = src[e], d = dst[e];
    float2 v = *(const float2*)(X + (size_t)s * 128 + c);
    float* p = msg + (size_t)d * 128 + c;
    unsafeAtomicAdd(p,     v.x);
    unsafeAtomicAdd(p + 1, v.y);
}

// Per-row: h = relu(LN(x + bmsg)*g + b) + feat, in-place over X (fp32).
// One wave (64 lanes) per row, D = 128.
__global__ __launch_bounds__(256) void ln_k(
    float* __restrict__ X, const float* __restrict__ bmsg,
    const float* __restrict__ feat, const float* __restrict__ g,
    const float* __restrict__ b, int M)
{
    int row = blockIdx.x * 4 + (threadIdx.x >> 6);
    int lane = threadIdx.x & 63;
    if (row >= M) return;
    size_t base = (size_t)row * 128;
    float x0 = X[base + lane]      + bmsg[lane];
    float x1 = X[base + 64 + lane] + bmsg[64 + lane];
    float s = x0 + x1;
#pragma unroll
    for (int o = 32; o > 0; o >>= 1) s += __shfl_xor(s, o, 64);
    float mean = s * 0.0078125f;
    float d0 = x0 - mean, d1 = x1 - mean;
    float q = d0 * d0 + d1 * d1;
#pragma unroll
    for (int o = 32; o > 0; o >>= 1) q += __shfl_xor(q, o, 64);
    float inv = rsqrtf(q * 0.0078125f + 1e-5f);
    float y0 = fmaxf(fmaf(d0 * inv, g[lane],      b[lane]),      0.f) + feat[base + lane];
    float y1 = fmaxf(fmaf(d1 * inv, g[64 + lane], b[64 + lane]), 0.f) + feat[base + 64 + lane];
    X[base + lane]      = y0;
    X[base + 64 + lane] = y1;
}

extern "C" void kernel_launch(void* const* d_in, const int* in_sizes, int n_in,
                              void* d_out, int out_size, void* d_ws, size_t ws_size,
                              hipStream_t stream)
{
    const float* feat_user   = (const float*)d_in[0];
    const float* feat_item   = (const float*)d_in[1];
    const float* W_u2i       = (const float*)d_in[2];
    const float* b_u2i       = (const float*)d_in[3];
    const float* W_i2u       = (const float*)d_in[4];
    const float* b_i2u       = (const float*)d_in[5];
    const float* self_w_user = (const float*)d_in[6];
    const float* self_w_item = (const float*)d_in[7];
    const float* ln_g_user   = (const float*)d_in[8];
    const float* ln_b_user   = (const float*)d_in[9];
    const float* ln_g_item   = (const float*)d_in[10];
    const float* ln_b_item   = (const float*)d_in[11];
    const float* ffn_w1      = (const float*)d_in[12];
    const float* ffn_b1      = (const float*)d_in[13];
    const float* ffn_w2      = (const float*)d_in[14];
    const float* ffn_b2      = (const float*)d_in[15];
    const int* src_u2i       = (const int*)d_in[16];
    const int* dst_u2i       = (const int*)d_in[17];
    const int* src_i2u       = (const int*)d_in[18];
    const int* dst_i2u       = (const int*)d_in[19];

    const int NU = in_sizes[0] / 128;
    const int NI = in_sizes[1] / 128;
    const int E  = in_sizes[16];

    // workspace layout (fp32): Xu | Xi | msgU | msgI ; hid reuses Xu+Xi (dead
    // after scatter); LN runs in-place on msgU/msgI. Total 102.4 MB.
    char* ws = (char*)d_ws;
    float* Xu   = (float*)(ws);
    float* Xi   = (float*)(ws + (size_t)NU * 128 * 4);
    float* msgU = (float*)(ws + (size_t)(NU + NI) * 128 * 4);
    float* msgI = (float*)(ws + (size_t)(2 * NU + NI) * 128 * 4);
    float* hid  = (float*)(ws);  // NU x 256 fp32 = 51.2 MB, fits Xu+Xi region

    float* out = (float*)d_out;

    dim3 blk(256);
    int gU = (NU + 63) / 64, gI = (NI + 63) / 64;

    // 1. relation transforms
    gemm_k<128, false, false, false><<<dim3(gU, 1), blk, 0, stream>>>(
        feat_user, W_u2i, nullptr, Xu, NU, 128);
    gemm_k<128, false, false, false><<<dim3(gI, 1), blk, 0, stream>>>(
        feat_item, W_i2u, nullptr, Xi, NI, 128);

    // 2. zero message accumulators (contiguous msgU|msgI)
    hipMemsetAsync(msgU, 0, (size_t)(NU + NI) * 128 * 4, stream);

    // 3. edge scatter (fp32 atomics)
    int sblocks = (int)(((long long)E * 64 + 255) / 256);
    scat_k<<<dim3(sblocks), blk, 0, stream>>>(Xu, src_u2i, dst_u2i, msgI, E);
    scat_k<<<dim3(sblocks), blk, 0, stream>>>(Xi, src_i2u, dst_i2u, msgU, E);

    // 4. self-loop transforms accumulate into msg
    gemm_k<128, true, false, false><<<dim3(gU, 1), blk, 0, stream>>>(
        feat_user, self_w_user, nullptr, msgU, NU, 128);
    gemm_k<128, true, false, false><<<dim3(gI, 1), blk, 0, stream>>>(
        feat_item, self_w_item, nullptr, msgI, NI, 128);

    // 5. LayerNorm -> ReLU -> residual (edge bias folded in), in-place
    ln_k<<<dim3((NU + 3) / 4), blk, 0, stream>>>(msgU, b_i2u, feat_user, ln_g_user, ln_b_user, NU);
    ln_k<<<dim3((NI + 3) / 4), blk, 0, stream>>>(msgI, b_u2i, feat_item, ln_g_item, ln_b_item, NI);

    // 6. FFN user: hid = relu(hU @ W1 + b1); out = hid @ W2 + b2
    gemm_k<128, false, true, true><<<dim3(gU, 2), blk, 0, stream>>>(
        msgU, ffn_w1, ffn_b1, hid, NU, 256);
    gemm_k<256, false, false, true><<<dim3(gU, 1), blk, 0, stream>>>(
        hid, ffn_w2, ffn_b2, out, NU, 128);

    // 7. FFN item
    gemm_k<128, false, true, true><<<dim3(gI, 2), blk, 0, stream>>>(
        msgI, ffn_w1, ffn_b1, hid, NI, 256);
    gemm_k<256, false, false, true><<<dim3(gI, 1), blk, 0, stream>>>(
        hid, ffn_w2, ffn_b2, out + (size_t)NU * 128, NI, 128);
}

// Round 3
// 747.278 us; speedup vs baseline: 2.0275x; 2.0275x over previous
//
#include <hip/hip_runtime.h>

// ---------------------------------------------------------------------------
// C[M x N] = A[M x K] @ W[K x N] (fp32), optional bias/relu. 256 thr, 64x128
// tile, per-thread 8x4. A staged in LDS, W streamed (L1/L2 resident).
// ---------------------------------------------------------------------------
template<int K, bool RELU, bool BIAS>
__global__ __launch_bounds__(256) void gemm_k(
    const float* __restrict__ A, const float* __restrict__ W,
    const float* __restrict__ bias, float* __restrict__ C,
    int M, int N)
{
    __shared__ float As[64 * K];
    const int tid = threadIdx.x;
    const int m0 = blockIdx.x * 64;

    const int AV = 64 * K / 4;
    float4* As4 = (float4*)As;
    for (int i = tid; i < AV; i += 256) {
        int row = i / (K / 4), c4 = i % (K / 4);
        int gr = m0 + row;
        float4 v = make_float4(0.f, 0.f, 0.f, 0.f);
        if (gr < M) v = ((const float4*)(A + (size_t)gr * K))[c4];
        As4[i] = v;
    }
    __syncthreads();

    const int tx = tid & 31, ty = tid >> 5;
    const int c0 = blockIdx.y * 128 + tx * 4;

    float acc[8][4];
#pragma unroll
    for (int r = 0; r < 8; r++) { acc[r][0]=0.f; acc[r][1]=0.f; acc[r][2]=0.f; acc[r][3]=0.f; }

    for (int k = 0; k < K; k += 4) {
        float bv[4][4];
#pragma unroll
        for (int kk = 0; kk < 4; kk++) {
            float4 w = *(const float4*)(W + (size_t)(k + kk) * N + c0);
            bv[kk][0] = w.x; bv[kk][1] = w.y; bv[kk][2] = w.z; bv[kk][3] = w.w;
        }
#pragma unroll
        for (int r = 0; r < 8; r++) {
            float4 av = *(const float4*)(&As[(ty * 8 + r) * K + k]);
#pragma unroll
            for (int c = 0; c < 4; c++) {
                acc[r][c] = fmaf(av.x, bv[0][c], acc[r][c]);
                acc[r][c] = fmaf(av.y, bv[1][c], acc[r][c]);
                acc[r][c] = fmaf(av.z, bv[2][c], acc[r][c]);
                acc[r][c] = fmaf(av.w, bv[3][c], acc[r][c]);
            }
        }
    }

    float bb[4] = {0.f, 0.f, 0.f, 0.f};
    if (BIAS) {
        float4 b4 = *(const float4*)(bias + c0);
        bb[0] = b4.x; bb[1] = b4.y; bb[2] = b4.z; bb[3] = b4.w;
    }

#pragma unroll
    for (int r = 0; r < 8; r++) {
        int gr = m0 + ty * 8 + r;
        if (gr >= M) continue;
        size_t base = (size_t)gr * N + c0;
        float v0 = acc[r][0] + bb[0], v1 = acc[r][1] + bb[1];
        float v2 = acc[r][2] + bb[2], v3 = acc[r][3] + bb[3];
        if (RELU) {
            v0 = fmaxf(v0, 0.f); v1 = fmaxf(v1, 0.f);
            v2 = fmaxf(v2, 0.f); v3 = fmaxf(v3, 0.f);
        }
        *(float4*)(C + base) = make_float4(v0, v1, v2, v3);
    }
}

// ---------------------------------------------------------------------------
// C = A0 @ W0 + A1 @ W1  (all K=N=128, fp32). Two sequential LDS phases
// reusing one 32 KB A-tile buffer; accumulators persist across phases.
// ---------------------------------------------------------------------------
__global__ __launch_bounds__(256) void gemm2_k(
    const float* __restrict__ A0, const float* __restrict__ W0,
    const float* __restrict__ A1, const float* __restrict__ W1,
    float* __restrict__ C, int M)
{
    __shared__ float As[64 * 128];
    const int tid = threadIdx.x;
    const int m0 = blockIdx.x * 64;
    const int tx = tid & 31, ty = tid >> 5;
    const int c0 = tx * 4;

    float acc[8][4];
#pragma unroll
    for (int r = 0; r < 8; r++) { acc[r][0]=0.f; acc[r][1]=0.f; acc[r][2]=0.f; acc[r][3]=0.f; }

    for (int p = 0; p < 2; p++) {
        const float* A = p ? A1 : A0;
        const float* W = p ? W1 : W0;
        __syncthreads();
        float4* As4 = (float4*)As;
        for (int i = tid; i < 64 * 32; i += 256) {
            int row = i / 32, c4 = i % 32;
            int gr = m0 + row;
            float4 v = make_float4(0.f, 0.f, 0.f, 0.f);
            if (gr < M) v = ((const float4*)(A + (size_t)gr * 128))[c4];
            As4[i] = v;
        }
        __syncthreads();

        for (int k = 0; k < 128; k += 4) {
            float bv[4][4];
#pragma unroll
            for (int kk = 0; kk < 4; kk++) {
                float4 w = *(const float4*)(W + (size_t)(k + kk) * 128 + c0);
                bv[kk][0] = w.x; bv[kk][1] = w.y; bv[kk][2] = w.z; bv[kk][3] = w.w;
            }
#pragma unroll
            for (int r = 0; r < 8; r++) {
                float4 av = *(const float4*)(&As[(ty * 8 + r) * 128 + k]);
#pragma unroll
                for (int c = 0; c < 4; c++) {
                    acc[r][c] = fmaf(av.x, bv[0][c], acc[r][c]);
                    acc[r][c] = fmaf(av.y, bv[1][c], acc[r][c]);
                    acc[r][c] = fmaf(av.z, bv[2][c], acc[r][c]);
                    acc[r][c] = fmaf(av.w, bv[3][c], acc[r][c]);
                }
            }
        }
    }

#pragma unroll
    for (int r = 0; r < 8; r++) {
        int gr = m0 + ty * 8 + r;
        if (gr >= M) continue;
        *(float4*)(C + (size_t)gr * 128 + c0) =
            make_float4(acc[r][0], acc[r][1], acc[r][2], acc[r][3]);
    }
}

// ---------------------------------------------------------------------------
// CSR build: histogram -> 3-phase exclusive scan -> place (counting sort).
// Both relations concatenated: buckets [0,NI) = item side, [NI,NI+NU) = user.
// ---------------------------------------------------------------------------
__global__ __launch_bounds__(256) void hist_k(
    const int* __restrict__ dst0, const int* __restrict__ dst1,
    int* __restrict__ cnt, int E, int NI)
{
    int t = blockIdx.x * 256 + threadIdx.x;
    if (t < E)          atomicAdd(&cnt[dst0[t]], 1);
    else if (t < 2 * E) atomicAdd(&cnt[NI + dst1[t - E]], 1);
}

__global__ __launch_bounds__(512) void scan1_k(
    const int* __restrict__ cnt, int* __restrict__ partials, int NR)
{
    __shared__ int s[512];
    int t = threadIdx.x, i = blockIdx.x * 512 + t;
    s[t] = (i < NR) ? cnt[i] : 0;
    __syncthreads();
    for (int off = 256; off > 0; off >>= 1) {
        if (t < off) s[t] += s[t + off];
        __syncthreads();
    }
    if (t == 0) partials[blockIdx.x] = s[0];
}

__global__ __launch_bounds__(256) void scan2_k(int* __restrict__ partials, int nb)
{
    __shared__ int s[256];
    int t = threadIdx.x;
    int v = (t < nb) ? partials[t] : 0;
    s[t] = v;
    __syncthreads();
    for (int off = 1; off < 256; off <<= 1) {
        int x = (t >= off) ? s[t - off] : 0;
        __syncthreads();
        s[t] += x;
        __syncthreads();
    }
    if (t < nb) partials[t] = s[t] - v;  // exclusive
}

__global__ __launch_bounds__(512) void scan3_k(
    const int* __restrict__ cnt, const int* __restrict__ partials,
    int* __restrict__ rowptr, int* __restrict__ head, int NR, int total)
{
    __shared__ int s[512];
    int t = threadIdx.x, i = blockIdx.x * 512 + t;
    int v = (i < NR) ? cnt[i] : 0;
    s[t] = v;
    __syncthreads();
    for (int off = 1; off < 512; off <<= 1) {
        int x = (t >= off) ? s[t - off] : 0;
        __syncthreads();
        s[t] += x;
        __syncthreads();
    }
    if (i < NR) {
        int excl = partials[blockIdx.x] + s[t] - v;
        rowptr[i] = excl;
        head[i] = excl;
    }
    if (i == 0) rowptr[NR] = total;
}

__global__ __launch_bounds__(256) void place_k(
    const int* __restrict__ src0, const int* __restrict__ dst0,
    const int* __restrict__ src1, const int* __restrict__ dst1,
    int* __restrict__ head, int* __restrict__ eidx, int E, int NI)
{
    int t = blockIdx.x * 256 + threadIdx.x;
    if (t < E) {
        int pos = atomicAdd(&head[dst0[t]], 1);
        eidx[pos] = src0[t];
    } else if (t < 2 * E) {
        int k = t - E;
        int pos = atomicAdd(&head[NI + dst1[k]], 1);
        eidx[pos] = src1[k];
    }
}

// ---------------------------------------------------------------------------
// Gather: S[r] = sum over edges of feat_src rows. One wave per row, D=128,
// float2 per lane, 2-deep index prefetch. Rows [0,NI): feat_user sources;
// rows [NI,NR): feat_item sources. Zero-degree rows write zeros.
// ---------------------------------------------------------------------------
__global__ __launch_bounds__(256) void gather_k(
    const int* __restrict__ rowptr, const int* __restrict__ eidx,
    const float* __restrict__ feat_user, const float* __restrict__ feat_item,
    float* __restrict__ S, int NI, int NR)
{
    int row = blockIdx.x * 4 + (threadIdx.x >> 6);
    int lane = threadIdx.x & 63;
    if (row >= NR) return;
    const float* F = (row < NI) ? feat_user : feat_item;
    int start = rowptr[row], end = rowptr[row + 1];
    int c = lane * 2;
    float a0 = 0.f, a1 = 0.f;
    int sn = (start < end) ? eidx[start] : 0;
    for (int j = start; j < end; j++) {
        int sc = sn;
        if (j + 1 < end) sn = eidx[j + 1];
        float2 v = *(const float2*)(F + (size_t)sc * 128 + c);
        a0 += v.x; a1 += v.y;
    }
    float2* o = (float2*)(S + (size_t)row * 128 + c);
    *o = make_float2(a0, a1);
}

// ---------------------------------------------------------------------------
// Per-row: h = relu(LN(x + bmsg)*g + b) + feat, in-place (fp32), wave/row.
// ---------------------------------------------------------------------------
__global__ __launch_bounds__(256) void ln_k(
    float* __restrict__ X, const float* __restrict__ bmsg,
    const float* __restrict__ feat, const float* __restrict__ g,
    const float* __restrict__ b, int M)
{
    int row = blockIdx.x * 4 + (threadIdx.x >> 6);
    int lane = threadIdx.x & 63;
    if (row >= M) return;
    size_t base = (size_t)row * 128;
    float x0 = X[base + lane]      + bmsg[lane];
    float x1 = X[base + 64 + lane] + bmsg[64 + lane];
    float s = x0 + x1;
#pragma unroll
    for (int o = 32; o > 0; o >>= 1) s += __shfl_xor(s, o, 64);
    float mean = s * 0.0078125f;
    float d0 = x0 - mean, d1 = x1 - mean;
    float q = d0 * d0 + d1 * d1;
#pragma unroll
    for (int o = 32; o > 0; o >>= 1) q += __shfl_xor(q, o, 64);
    float inv = rsqrtf(q * 0.0078125f + 1e-5f);
    float y0 = fmaxf(fmaf(d0 * inv, g[lane],      b[lane]),      0.f) + feat[base + lane];
    float y1 = fmaxf(fmaf(d1 * inv, g[64 + lane], b[64 + lane]), 0.f) + feat[base + 64 + lane];
    X[base + lane]      = y0;
    X[base + 64 + lane] = y1;
}

extern "C" void kernel_launch(void* const* d_in, const int* in_sizes, int n_in,
                              void* d_out, int out_size, void* d_ws, size_t ws_size,
                              hipStream_t stream)
{
    const float* feat_user   = (const float*)d_in[0];
    const float* feat_item   = (const float*)d_in[1];
    const float* W_u2i       = (const float*)d_in[2];
    const float* b_u2i       = (const float*)d_in[3];
    const float* W_i2u       = (const float*)d_in[4];
    const float* b_i2u       = (const float*)d_in[5];
    const float* self_w_user = (const float*)d_in[6];
    const float* self_w_item = (const float*)d_in[7];
    const float* ln_g_user   = (const float*)d_in[8];
    const float* ln_b_user   = (const float*)d_in[9];
    const float* ln_g_item   = (const float*)d_in[10];
    const float* ln_b_item   = (const float*)d_in[11];
    const float* ffn_w1      = (const float*)d_in[12];
    const float* ffn_b1      = (const float*)d_in[13];
    const float* ffn_w2      = (const float*)d_in[14];
    const float* ffn_b2      = (const float*)d_in[15];
    const int* src_u2i       = (const int*)d_in[16];
    const int* dst_u2i       = (const int*)d_in[17];
    const int* src_i2u       = (const int*)d_in[18];
    const int* dst_i2u       = (const int*)d_in[19];

    const int NU = in_sizes[0] / 128;
    const int NI = in_sizes[1] / 128;
    const int E  = in_sizes[16];
    const int NR = NI + NU;          // concatenated rows: [0,NI)=item, [NI,NR)=user

    // Workspace (102.4 MB total, same footprint as round 2):
    //   region A [0, NR*512): S (gather output) -> later reused as FFN hidden
    //   region B [NR*512, 2*NR*512): CSR arrays (6 MB, dead after gather)
    //                                -> then msgI | msgU (51.2 MB)
    char* ws = (char*)d_ws;
    size_t A_bytes = (size_t)NR * 128 * 4;
    float* S    = (float*)ws;
    char*  B    = ws + A_bytes;
    float* msgI = (float*)B;                              // NI x 128
    float* msgU = (float*)(B + (size_t)NI * 128 * 4);     // NU x 128
    int* cnt      = (int*)B;
    int* rowptr   = cnt + NR;
    int* head     = rowptr + NR + 1;
    int* partials = head + NR;
    int* eidx     = partials + 256;
    float* hid  = (float*)ws;  // NR/2 x 256 fp32 per side, reuses region A

    float* out = (float*)d_out;
    dim3 blk(256);
    const int nchunk = (NR + 511) / 512;
    const int eg = (2 * E + 255) / 256;

    // --- CSR build (counting sort by dst, both relations concatenated) ---
    hipMemsetAsync(cnt, 0, (size_t)NR * 4, stream);
    hist_k<<<dim3(eg), blk, 0, stream>>>(dst_u2i, dst_i2u, cnt, E, NI);
    scan1_k<<<dim3(nchunk), dim3(512), 0, stream>>>(cnt, partials, NR);
    scan2_k<<<dim3(1), blk, 0, stream>>>(partials, nchunk);
    scan3_k<<<dim3(nchunk), dim3(512), 0, stream>>>(cnt, partials, rowptr, head, NR, 2 * E);
    place_k<<<dim3(eg), blk, 0, stream>>>(src_u2i, dst_u2i, src_i2u, dst_i2u, head, eidx, E, NI);

    // --- Gather raw-feature sums per destination (linearity of segment_sum) ---
    gather_k<<<dim3((NR + 3) / 4), blk, 0, stream>>>(
        rowptr, eidx, feat_user, feat_item, S, NI, NR);

    // --- Fused message + self-loop GEMMs: msg = S@W_rel + feat@W_self ---
    int gU = (NU + 63) / 64, gI = (NI + 63) / 64;
    gemm2_k<<<dim3(gI), blk, 0, stream>>>(S, W_u2i, feat_item, self_w_item, msgI, NI);
    gemm2_k<<<dim3(gU), blk, 0, stream>>>(S + (size_t)NI * 128, W_i2u, feat_user, self_w_user, msgU, NU);

    // --- LayerNorm -> ReLU -> residual (edge bias folded in), in-place ---
    ln_k<<<dim3((NU + 3) / 4), blk, 0, stream>>>(msgU, b_i2u, feat_user, ln_g_user, ln_b_user, NU);
    ln_k<<<dim3((NI + 3) / 4), blk, 0, stream>>>(msgI, b_u2i, feat_item, ln_g_item, ln_b_item, NI);

    // --- FFN user ---
    gemm_k<128, true, true><<<dim3(gU, 2), blk, 0, stream>>>(msgU, ffn_w1, ffn_b1, hid, NU, 256);
    gemm_k<256, false, true><<<dim3(gU, 1), blk, 0, stream>>>(hid, ffn_w2, ffn_b2, out, NU, 128);

    // --- FFN item ---
    gemm_k<128, true, true><<<dim3(gI, 2), blk, 0, stream>>>(msgI, ffn_w1, ffn_b1, hid, NI, 256);
    gemm_k<256, false, true><<<dim3(gI, 1), blk, 0, stream>>>(hid, ffn_w2, ffn_b2, out + (size_t)NU * 128, NI, 128);
}

// Round 5
// 516.084 us; speedup vs baseline: 2.9357x; 1.4480x over previous
//
#include <hip/hip_runtime.h>

typedef unsigned short u16;
typedef __attribute__((ext_vector_type(4))) float f32x4;
typedef __attribute__((ext_vector_type(8))) short bf16x8;

__device__ __forceinline__ float bf2f(u16 u) {
    union { unsigned int i; float f; } v; v.i = ((unsigned int)u) << 16; return v.f;
}
__device__ __forceinline__ u16 f2bf(float f) {
    union { float f; unsigned int i; } v; v.f = f;
    unsigned int r = v.i + 0x7fffu + ((v.i >> 16) & 1u);
    return (u16)(r >> 16);
}
// async global->LDS, 16B per lane; LDS dest is wave-uniform base + lane*16
__device__ __forceinline__ void gload16(const void* g, void* l) {
    __builtin_amdgcn_global_load_lds(
        (const __attribute__((address_space(1))) unsigned int*)g,
        (__attribute__((address_space(3))) unsigned int*)l, 16, 0, 0);
}

// ---------------------------------------------------------------------------
// MFMA GEMM: C[M x N] = sum_ch A_ch @ W_ch^T (+bias, relu). bf16 in, fp32 acc.
// 256 thr = 4 waves; 128x128 C tile per block; wave = 64x64 (4x4 MFMA tiles).
// A_ch: [M x 128] bf16 rows (stride sA elements). W_ch: W^T rows [N x 128]
// (stride sW). K per chunk = 128. nch chunks (dual-GEMM / K=256 via chunks).
// ---------------------------------------------------------------------------
template<bool RELU, bool BIAS, bool OUTBF>
__global__ __launch_bounds__(256) void mg_k(
    const u16* __restrict__ A0, const u16* __restrict__ A1,
    const u16* __restrict__ W0, const u16* __restrict__ W1,
    int sA, int sW, int nch, const float* __restrict__ bias,
    float* __restrict__ Cf, u16* __restrict__ Cb, int M, int N)
{
    __shared__ __align__(16) u16 As[128 * 128];
    __shared__ __align__(16) u16 Ws[128 * 128];
    const int tid = threadIdx.x, w = tid >> 6, l = tid & 63;
    const int m0 = blockIdx.x * 128, n0 = blockIdx.y * 128;
    const int wr = (w >> 1) * 64, wc = (w & 1) * 64;
    const int quad = l >> 4, lan = l & 15;

    f32x4 acc[4][4];
#pragma unroll
    for (int i = 0; i < 4; i++)
#pragma unroll
        for (int j = 0; j < 4; j++) acc[i][j] = (f32x4){0.f, 0.f, 0.f, 0.f};

    for (int ch = 0; ch < nch; ch++) {
        const u16* Ab = ch ? A1 : A0;
        const u16* Wb = ch ? W1 : W0;
        if (ch) __syncthreads();
#pragma unroll
        for (int it = 0; it < 8; it++) {
            int o = ((it * 4 + w) * 64 + l) * 16;   // byte offset in 32KB tile
            int row = o >> 8, cb = o & 255;         // tile row, col-byte
            int gr = m0 + row; if (gr >= M) gr = M - 1;   // clamp: OOB rows unused
            gload16(Ab + (size_t)gr * sA + (cb >> 1), (char*)As + o);
            gload16(Wb + (size_t)(n0 + row) * sW + (cb >> 1), (char*)Ws + o);
        }
        __syncthreads();
#pragma unroll
        for (int kk = 0; kk < 4; kk++) {
            bf16x8 af[4], bfr[4];
#pragma unroll
            for (int i = 0; i < 4; i++)
                af[i] = *(const bf16x8*)&As[(wr + i * 16 + lan) * 128 + kk * 32 + quad * 8];
#pragma unroll
            for (int j = 0; j < 4; j++)
                bfr[j] = *(const bf16x8*)&Ws[(wc + j * 16 + lan) * 128 + kk * 32 + quad * 8];
#pragma unroll
            for (int i = 0; i < 4; i++)
#pragma unroll
                for (int j = 0; j < 4; j++)
                    acc[i][j] = __builtin_amdgcn_mfma_f32_16x16x32_bf16(
                        af[i], bfr[j], acc[i][j], 0, 0, 0);
        }
    }

#pragma unroll
    for (int j = 0; j < 4; j++) {
        int col = n0 + wc + j * 16 + lan;
        float bb = BIAS ? bias[col] : 0.f;
#pragma unroll
        for (int i = 0; i < 4; i++) {
            int row0 = m0 + wr + i * 16 + quad * 4;
#pragma unroll
            for (int r = 0; r < 4; r++) {
                int gr = row0 + r;
                if (gr < M) {
                    float v = acc[i][j][r] + bb;
                    if (RELU) v = fmaxf(v, 0.f);
                    if (OUTBF) Cb[(size_t)gr * N + col] = f2bf(v);
                    else       Cf[(size_t)gr * N + col] = v;
                }
            }
        }
    }
}

// ---------------------------------------------------------------------------
// fp32 -> bf16 casts for both feature tables (vec4)
// ---------------------------------------------------------------------------
__global__ __launch_bounds__(256) void cast2_k(
    const float* __restrict__ fu, const float* __restrict__ fi,
    u16* __restrict__ bu, u16* __restrict__ bi, int nu4, int ni4)
{
    int t = blockIdx.x * 256 + threadIdx.x;
    const float* X; u16* Y; int idx;
    if (t < nu4) { X = fu; Y = bu; idx = t; }
    else if (t < nu4 + ni4) { X = fi; Y = bi; idx = t - nu4; }
    else return;
    float4 v = ((const float4*)X)[idx];
    ushort4 o = make_ushort4(f2bf(v.x), f2bf(v.y), f2bf(v.z), f2bf(v.w));
    ((ushort4*)Y)[idx] = o;
}

// ---------------------------------------------------------------------------
// All 6 weight transposes (fp32 W[K][N] -> bf16 WT[N][K]) in one launch.
// layout: 4 x (128x128) then ffn_w1 (128x256) then ffn_w2 (256x128).
// ---------------------------------------------------------------------------
__global__ __launch_bounds__(256) void wt6_k(
    const float* __restrict__ w0, const float* __restrict__ w1,
    const float* __restrict__ w2, const float* __restrict__ w3,
    const float* __restrict__ w4, const float* __restrict__ w5,
    u16* __restrict__ o0, u16* __restrict__ o1, u16* __restrict__ o2,
    u16* __restrict__ o3, u16* __restrict__ o4, u16* __restrict__ o5)
{
    int t = blockIdx.x * 256 + threadIdx.x;
    const float* W; u16* O; int K, N, idx;
    if (t < 65536) {
        int s = t >> 14; idx = t & 16383; K = 128; N = 128;
        W = s == 0 ? w0 : s == 1 ? w1 : s == 2 ? w2 : w3;
        O = s == 0 ? o0 : s == 1 ? o1 : s == 2 ? o2 : o3;
    } else {
        int u = t - 65536; int s = u >> 15; idx = u & 32767;
        if (s == 0) { W = w4; O = o4; K = 128; N = 256; }
        else        { W = w5; O = o5; K = 256; N = 128; }
    }
    int k = idx / N, n = idx % N;
    O[n * K + k] = f2bf(W[idx]);
}

// ---------------------------------------------------------------------------
// CSR build (counting sort by dst; both relations concatenated)
// ---------------------------------------------------------------------------
__global__ __launch_bounds__(256) void hist_k(
    const int* __restrict__ dst0, const int* __restrict__ dst1,
    int* __restrict__ cnt, int E, int NI)
{
    int t = blockIdx.x * 256 + threadIdx.x;
    if (t < E)          atomicAdd(&cnt[dst0[t]], 1);
    else if (t < 2 * E) atomicAdd(&cnt[NI + dst1[t - E]], 1);
}

__global__ __launch_bounds__(512) void scan1_k(
    const int* __restrict__ cnt, int* __restrict__ partials, int NR)
{
    __shared__ int s[512];
    int t = threadIdx.x, i = blockIdx.x * 512 + t;
    s[t] = (i < NR) ? cnt[i] : 0;
    __syncthreads();
    for (int off = 256; off > 0; off >>= 1) {
        if (t < off) s[t] += s[t + off];
        __syncthreads();
    }
    if (t == 0) partials[blockIdx.x] = s[0];
}

__global__ __launch_bounds__(256) void scan2_k(int* __restrict__ partials, int nb)
{
    __shared__ int s[256];
    int t = threadIdx.x;
    int v = (t < nb) ? partials[t] : 0;
    s[t] = v;
    __syncthreads();
    for (int off = 1; off < 256; off <<= 1) {
        int x = (t >= off) ? s[t - off] : 0;
        __syncthreads();
        s[t] += x;
        __syncthreads();
    }
    if (t < nb) partials[t] = s[t] - v;  // exclusive
}

__global__ __launch_bounds__(512) void scan3_k(
    const int* __restrict__ cnt, const int* __restrict__ partials,
    int* __restrict__ rowptr, int* __restrict__ head, int NR, int total)
{
    __shared__ int s[512];
    int t = threadIdx.x, i = blockIdx.x * 512 + t;
    int v = (i < NR) ? cnt[i] : 0;
    s[t] = v;
    __syncthreads();
    for (int off = 1; off < 512; off <<= 1) {
        int x = (t >= off) ? s[t - off] : 0;
        __syncthreads();
        s[t] += x;
        __syncthreads();
    }
    if (i < NR) {
        int excl = partials[blockIdx.x] + s[t] - v;
        rowptr[i] = excl;
        head[i] = excl;
    }
    if (i == 0) rowptr[NR] = total;
}

__global__ __launch_bounds__(256) void place_k(
    const int* __restrict__ src0, const int* __restrict__ dst0,
    const int* __restrict__ src1, const int* __restrict__ dst1,
    int* __restrict__ head, int* __restrict__ eidx, int E, int NI)
{
    int t = blockIdx.x * 256 + threadIdx.x;
    if (t < E) {
        int pos = atomicAdd(&head[dst0[t]], 1);
        eidx[pos] = src0[t];
    } else if (t < 2 * E) {
        int k = t - E;
        int pos = atomicAdd(&head[NI + dst1[k]], 1);
        eidx[pos] = src1[k];
    }
}

// ---------------------------------------------------------------------------
// Gather: S[r] = sum of bf16 feature rows (fp32 acc, bf16 out). Wave per row.
// ---------------------------------------------------------------------------
__global__ __launch_bounds__(256) void gather_k(
    const int* __restrict__ rowptr, const int* __restrict__ eidx,
    const u16* __restrict__ fu, const u16* __restrict__ fi,
    u16* __restrict__ S, int NI, int NR)
{
    int row = blockIdx.x * 4 + (threadIdx.x >> 6);
    int lane = threadIdx.x & 63;
    if (row >= NR) return;
    const u16* F = (row < NI) ? fu : fi;
    int start = rowptr[row], end = rowptr[row + 1];
    int c = lane * 2;
    float a0 = 0.f, a1 = 0.f;
    int sn = (start < end) ? eidx[start] : 0;
    for (int j = start; j < end; j++) {
        int sc = sn;
        if (j + 1 < end) sn = eidx[j + 1];
        unsigned int v = *(const unsigned int*)(F + (size_t)sc * 128 + c);
        a0 += bf2f((u16)(v & 0xffffu));
        a1 += bf2f((u16)(v >> 16));
    }
    unsigned int o = ((unsigned int)f2bf(a1) << 16) | (unsigned int)f2bf(a0);
    *(unsigned int*)(S + (size_t)row * 128 + c) = o;
}

// ---------------------------------------------------------------------------
// h = relu(LN(msg + bmsg)*g + b) + feat  (msg bf16, feat fp32, out bf16)
// ---------------------------------------------------------------------------
__global__ __launch_bounds__(256) void ln_k(
    const u16* __restrict__ X, const float* __restrict__ bmsg,
    const float* __restrict__ feat, const float* __restrict__ g,
    const float* __restrict__ b, u16* __restrict__ H, int M)
{
    int row = blockIdx.x * 4 + (threadIdx.x >> 6);
    int lane = threadIdx.x & 63;
    if (row >= M) return;
    size_t base = (size_t)row * 128;
    float x0 = bf2f(X[base + lane])      + bmsg[lane];
    float x1 = bf2f(X[base + 64 + lane]) + bmsg[64 + lane];
    float s = x0 + x1;
#pragma unroll
    for (int o = 32; o > 0; o >>= 1) s += __shfl_xor(s, o, 64);
    float mean = s * 0.0078125f;
    float d0 = x0 - mean, d1 = x1 - mean;
    float q = d0 * d0 + d1 * d1;
#pragma unroll
    for (int o = 32; o > 0; o >>= 1) q += __shfl_xor(q, o, 64);
    float inv = rsqrtf(q * 0.0078125f + 1e-5f);
    float y0 = fmaxf(fmaf(d0 * inv, g[lane],      b[lane]),      0.f) + feat[base + lane];
    float y1 = fmaxf(fmaf(d1 * inv, g[64 + lane], b[64 + lane]), 0.f) + feat[base + 64 + lane];
    H[base + lane]      = f2bf(y0);
    H[base + 64 + lane] = f2bf(y1);
}

extern "C" void kernel_launch(void* const* d_in, const int* in_sizes, int n_in,
                              void* d_out, int out_size, void* d_ws, size_t ws_size,
                              hipStream_t stream)
{
    const float* feat_user   = (const float*)d_in[0];
    const float* feat_item   = (const float*)d_in[1];
    const float* W_u2i       = (const float*)d_in[2];
    const float* b_u2i       = (const float*)d_in[3];
    const float* W_i2u       = (const float*)d_in[4];
    const float* b_i2u       = (const float*)d_in[5];
    const float* self_w_user = (const float*)d_in[6];
    const float* self_w_item = (const float*)d_in[7];
    const float* ln_g_user   = (const float*)d_in[8];
    const float* ln_b_user   = (const float*)d_in[9];
    const float* ln_g_item   = (const float*)d_in[10];
    const float* ln_b_item   = (const float*)d_in[11];
    const float* ffn_w1      = (const float*)d_in[12];
    const float* ffn_b1      = (const float*)d_in[13];
    const float* ffn_w2      = (const float*)d_in[14];
    const float* ffn_b2      = (const float*)d_in[15];
    const int* src_u2i       = (const int*)d_in[16];
    const int* dst_u2i       = (const int*)d_in[17];
    const int* src_i2u       = (const int*)d_in[18];
    const int* dst_i2u       = (const int*)d_in[19];

    const int NU = in_sizes[0] / 128;
    const int NI = in_sizes[1] / 128;
    const int E  = in_sizes[16];
    const int NR = NI + NU;   // rows: [0,NI)=item dst (user srcs), [NI,NR)=user dst

    // Workspace (~77 MB):
    //  R0 [25.6MB]: S_bf (gather out)        -> hid (FFN hidden, per side)
    //  R1 [25.6MB]: featU_bf | featI_bf      -> hU | hI (LN out)
    //  R2 [25.6MB]: CSR arrays (6MB)         -> msgI | msgU (bf16)
    //  R3 [0.26MB]: transposed bf16 weights (live whole launch)
    char* ws = (char*)d_ws;
    size_t R0sz = (size_t)NR * 128 * 2;
    size_t hidsz = (size_t)(NU > NI ? NU : NI) * 256 * 2;
    if (hidsz > R0sz) R0sz = hidsz;
    char* R0 = ws;
    char* R1 = R0 + R0sz;
    char* R2 = R1 + (size_t)NR * 128 * 2;
    char* R3 = R2 + (size_t)NR * 128 * 2;

    u16* Sb   = (u16*)R0;
    u16* hid  = (u16*)R0;
    u16* fub  = (u16*)R1;
    u16* fib  = fub + (size_t)NU * 128;
    u16* hU   = (u16*)R1;
    u16* hI   = hU + (size_t)NU * 128;
    u16* msgI = (u16*)R2;
    u16* msgU = msgI + (size_t)NI * 128;
    int* cnt      = (int*)R2;
    int* rowptr   = cnt + NR;
    int* head     = rowptr + NR + 1;
    int* partials = head + NR;
    int* eidx     = partials + 256;
    u16* w_u2iT = (u16*)R3;
    u16* w_i2uT = w_u2iT + 16384;
    u16* selfUT = w_i2uT + 16384;
    u16* selfIT = selfUT + 16384;
    u16* ffn1T  = selfIT + 16384;   // [256][128]
    u16* ffn2T  = ffn1T + 32768;    // [128][256]

    float* out = (float*)d_out;
    dim3 blk(256);
    const int nchunk = (NR + 511) / 512;
    const int eg = (2 * E + 255) / 256;
    const int nu4 = NU * 128 / 4, ni4 = NI * 128 / 4;

    // --- dtype prep ---
    cast2_k<<<dim3((nu4 + ni4 + 255) / 256), blk, 0, stream>>>(
        feat_user, feat_item, fub, fib, nu4, ni4);
    wt6_k<<<dim3(512), blk, 0, stream>>>(
        W_u2i, W_i2u, self_w_user, self_w_item, ffn_w1, ffn_w2,
        w_u2iT, w_i2uT, selfUT, selfIT, ffn1T, ffn2T);

    // --- CSR build ---
    (void)hipMemsetAsync(cnt, 0, (size_t)NR * 4, stream);
    hist_k<<<dim3(eg), blk, 0, stream>>>(dst_u2i, dst_i2u, cnt, E, NI);
    scan1_k<<<dim3(nchunk), dim3(512), 0, stream>>>(cnt, partials, NR);
    scan2_k<<<dim3(1), blk, 0, stream>>>(partials, nchunk);
    scan3_k<<<dim3(nchunk), dim3(512), 0, stream>>>(cnt, partials, rowptr, head, NR, 2 * E);
    place_k<<<dim3(eg), blk, 0, stream>>>(src_u2i, dst_u2i, src_i2u, dst_i2u, head, eidx, E, NI);

    // --- gather raw-feature sums (linearity of segment_sum) ---
    gather_k<<<dim3((NR + 3) / 4), blk, 0, stream>>>(rowptr, eidx, fub, fib, Sb, NI, NR);

    // --- msg = S @ W_rel^T + feat @ W_self^T (dual-GEMM, bf16 out) ---
    int gU = (NU + 127) / 128, gI = (NI + 127) / 128;
    mg_k<false, false, true><<<dim3(gI, 1), blk, 0, stream>>>(
        Sb, fib, w_u2iT, selfIT, 128, 128, 2, nullptr, nullptr, msgI, NI, 128);
    mg_k<false, false, true><<<dim3(gU, 1), blk, 0, stream>>>(
        Sb + (size_t)NI * 128, fub, w_i2uT, selfUT, 128, 128, 2, nullptr, nullptr, msgU, NU, 128);

    // --- LN -> ReLU -> residual ---
    ln_k<<<dim3((NU + 3) / 4), blk, 0, stream>>>(msgU, b_i2u, feat_user, ln_g_user, ln_b_user, hU, NU);
    ln_k<<<dim3((NI + 3) / 4), blk, 0, stream>>>(msgI, b_u2i, feat_item, ln_g_item, ln_b_item, hI, NI);

    // --- FFN user ---
    mg_k<true, true, true><<<dim3(gU, 2), blk, 0, stream>>>(
        hU, nullptr, ffn1T, nullptr, 128, 128, 1, ffn_b1, nullptr, hid, NU, 256);
    mg_k<false, true, false><<<dim3(gU, 1), blk, 0, stream>>>(
        hid, hid + 128, ffn2T, ffn2T + 128, 256, 256, 2, ffn_b2, out, nullptr, NU, 128);

    // --- FFN item ---
    mg_k<true, true, true><<<dim3(gI, 2), blk, 0, stream>>>(
        hI, nullptr, ffn1T, nullptr, 128, 128, 1, ffn_b1, nullptr, hid, NI, 256);
    mg_k<false, true, false><<<dim3(gI, 1), blk, 0, stream>>>(
        hid, hid + 128, ffn2T, ffn2T + 128, 256, 256, 2, ffn_b2,
        out + (size_t)NU * 128, nullptr, NI, 128);
}

// Round 6
// 389.449 us; speedup vs baseline: 3.8903x; 1.3252x over previous
//
#include <hip/hip_runtime.h>

typedef unsigned short u16;
typedef __attribute__((ext_vector_type(4))) float f32x4;
typedef __attribute__((ext_vector_type(8))) short bf16x8;

#define MAXB 512      // max coarse buckets supported by one scan block
#define BUK  256      // dst rows per bucket
#define EMAX 4096     // max edges per bucket (mean 3072, ~18 sigma headroom)

__device__ __forceinline__ float bf2f(u16 u) {
    union { unsigned int i; float f; } v; v.i = ((unsigned int)u) << 16; return v.f;
}
__device__ __forceinline__ u16 f2bf(float f) {
    union { float f; unsigned int i; } v; v.f = f;
    unsigned int r = v.i + 0x7fffu + ((v.i >> 16) & 1u);
    return (u16)(r >> 16);
}
__device__ __forceinline__ void gload16(const void* g, void* l) {
    __builtin_amdgcn_global_load_lds(
        (const __attribute__((address_space(1))) unsigned int*)g,
        (__attribute__((address_space(3))) unsigned int*)l, 16, 0, 0);
}

// ---------------------------------------------------------------------------
// MFMA GEMM: C[M x N] = sum_ch A_ch @ W_ch^T (+bias, relu). bf16 in, fp32 acc.
// 256 thr = 4 waves; 128x128 C tile; wave = 64x64 (4x4 of 16x16x32 MFMA).
// ---------------------------------------------------------------------------
template<bool RELU, bool BIAS, bool OUTBF>
__global__ __launch_bounds__(256) void mg_k(
    const u16* __restrict__ A0, const u16* __restrict__ A1,
    const u16* __restrict__ W0, const u16* __restrict__ W1,
    int sA, int sW, int nch, const float* __restrict__ bias,
    float* __restrict__ Cf, u16* __restrict__ Cb, int M, int N)
{
    __shared__ __align__(16) u16 As[128 * 128];
    __shared__ __align__(16) u16 Ws[128 * 128];
    const int tid = threadIdx.x, w = tid >> 6, l = tid & 63;
    const int m0 = blockIdx.x * 128, n0 = blockIdx.y * 128;
    const int wr = (w >> 1) * 64, wc = (w & 1) * 64;
    const int quad = l >> 4, lan = l & 15;

    f32x4 acc[4][4];
#pragma unroll
    for (int i = 0; i < 4; i++)
#pragma unroll
        for (int j = 0; j < 4; j++) acc[i][j] = (f32x4){0.f, 0.f, 0.f, 0.f};

    for (int ch = 0; ch < nch; ch++) {
        const u16* Ab = ch ? A1 : A0;
        const u16* Wb = ch ? W1 : W0;
        if (ch) __syncthreads();
#pragma unroll
        for (int it = 0; it < 8; it++) {
            int o = ((it * 4 + w) * 64 + l) * 16;
            int row = o >> 8, cb = o & 255;
            int gr = m0 + row; if (gr >= M) gr = M - 1;
            gload16(Ab + (size_t)gr * sA + (cb >> 1), (char*)As + o);
            gload16(Wb + (size_t)(n0 + row) * sW + (cb >> 1), (char*)Ws + o);
        }
        __syncthreads();
#pragma unroll
        for (int kk = 0; kk < 4; kk++) {
            bf16x8 af[4], bfr[4];
#pragma unroll
            for (int i = 0; i < 4; i++)
                af[i] = *(const bf16x8*)&As[(wr + i * 16 + lan) * 128 + kk * 32 + quad * 8];
#pragma unroll
            for (int j = 0; j < 4; j++)
                bfr[j] = *(const bf16x8*)&Ws[(wc + j * 16 + lan) * 128 + kk * 32 + quad * 8];
#pragma unroll
            for (int i = 0; i < 4; i++)
#pragma unroll
                for (int j = 0; j < 4; j++)
                    acc[i][j] = __builtin_amdgcn_mfma_f32_16x16x32_bf16(
                        af[i], bfr[j], acc[i][j], 0, 0, 0);
        }
    }

#pragma unroll
    for (int j = 0; j < 4; j++) {
        int col = n0 + wc + j * 16 + lan;
        float bb = BIAS ? bias[col] : 0.f;
#pragma unroll
        for (int i = 0; i < 4; i++) {
            int row0 = m0 + wr + i * 16 + quad * 4;
#pragma unroll
            for (int r = 0; r < 4; r++) {
                int gr = row0 + r;
                if (gr < M) {
                    float v = acc[i][j][r] + bb;
                    if (RELU) v = fmaxf(v, 0.f);
                    if (OUTBF) Cb[(size_t)gr * N + col] = f2bf(v);
                    else       Cf[(size_t)gr * N + col] = v;
                }
            }
        }
    }
}

// ---------------------------------------------------------------------------
// prep: feature fp32->bf16 casts (vec4) + all 6 weight transposes, fused.
// ---------------------------------------------------------------------------
__global__ __launch_bounds__(256) void prep_k(
    const float* __restrict__ fu, const float* __restrict__ fi,
    u16* __restrict__ bu, u16* __restrict__ bi, int nu4, int ni4,
    const float* __restrict__ w0, const float* __restrict__ w1,
    const float* __restrict__ w2, const float* __restrict__ w3,
    const float* __restrict__ w4, const float* __restrict__ w5,
    u16* __restrict__ o0, u16* __restrict__ o1, u16* __restrict__ o2,
    u16* __restrict__ o3, u16* __restrict__ o4, u16* __restrict__ o5)
{
    int t = blockIdx.x * 256 + threadIdx.x;
    int nc = nu4 + ni4;
    if (t < nc) {
        const float* X; u16* Y; int idx;
        if (t < nu4) { X = fu; Y = bu; idx = t; }
        else { X = fi; Y = bi; idx = t - nu4; }
        float4 v = ((const float4*)X)[idx];
        ((ushort4*)Y)[idx] = make_ushort4(f2bf(v.x), f2bf(v.y), f2bf(v.z), f2bf(v.w));
        return;
    }
    int u = t - nc;
    const float* W; u16* O; int K, N, idx;
    if (u < 65536) {
        int s = u >> 14; idx = u & 16383; K = 128; N = 128;
        W = s == 0 ? w0 : s == 1 ? w1 : s == 2 ? w2 : w3;
        O = s == 0 ? o0 : s == 1 ? o1 : s == 2 ? o2 : o3;
    } else if (u < 65536 + 65536) {
        int v2 = u - 65536; int s = v2 >> 15; idx = v2 & 32767;
        if (s == 0) { W = w4; O = o4; K = 128; N = 256; }
        else        { W = w5; O = o5; K = 256; N = 128; }
    } else return;
    int k = idx / N, n = idx % N;
    O[n * K + k] = f2bf(W[idx]);
}

// ---------------------------------------------------------------------------
// Coarse bucket histogram (buckets of BUK dst rows), LDS-aggregated.
// ---------------------------------------------------------------------------
__global__ __launch_bounds__(256) void chist_k(
    const int* __restrict__ dst0, const int* __restrict__ dst1,
    int* __restrict__ cnt, int E, int NI, int NBUK)
{
    __shared__ int lh[MAXB];
    int t = threadIdx.x;
    for (int i = t; i < MAXB; i += 256) lh[i] = 0;
    __syncthreads();
    for (long long e = (long long)blockIdx.x * 256 + t; e < 2LL * E;
         e += (long long)gridDim.x * 256) {
        int row = (e < E) ? dst0[e] : NI + dst1[e - E];
        atomicAdd(&lh[row >> 8], 1);
    }
    __syncthreads();
    for (int i = t; i < NBUK; i += 256)
        if (lh[i]) atomicAdd(&cnt[i], lh[i]);
}

// ---------------------------------------------------------------------------
// Single-block exclusive scan over NBUK buckets -> crp, chead; rowptr[NR].
// ---------------------------------------------------------------------------
__global__ __launch_bounds__(512) void cscan_k(
    const int* __restrict__ cnt, int* __restrict__ crp, int* __restrict__ chead,
    int* __restrict__ rowptr, int NBUK, int NR)
{
    __shared__ int s[512];
    int t = threadIdx.x;
    int carry = 0;
    for (int base = 0; base < NBUK; base += 512) {
        int i = base + t;
        int v = (i < NBUK) ? cnt[i] : 0;
        s[t] = v;
        __syncthreads();
        for (int off = 1; off < 512; off <<= 1) {
            int x = (t >= off) ? s[t - off] : 0;
            __syncthreads();
            s[t] += x;
            __syncthreads();
        }
        int excl = s[t] - v + carry;
        if (i < NBUK) { crp[i] = excl; chead[i] = excl; }
        carry += s[511];
        __syncthreads();
    }
    if (t == 0) { crp[NBUK] = carry; rowptr[NR] = carry; }
}

// ---------------------------------------------------------------------------
// Partition edges into coarse buckets with block-aggregated reservations.
// Packed edge: (dst_local << 16) | src   (both < 65536).
// ---------------------------------------------------------------------------
__global__ __launch_bounds__(256) void cpart_k(
    const int* __restrict__ src0, const int* __restrict__ dst0,
    const int* __restrict__ src1, const int* __restrict__ dst1,
    int* __restrict__ chead, unsigned int* __restrict__ ebuf,
    int E, int NI, int NBUK)
{
    __shared__ int lh[MAXB], lb[MAXB], lo[MAXB];
    int t = threadIdx.x;
    long long total = 2LL * E;
    long long per = (total + gridDim.x - 1) / gridDim.x;
    long long r0 = (long long)blockIdx.x * per;
    long long r1 = r0 + per; if (r1 > total) r1 = total;

    for (int i = t; i < MAXB; i += 256) { lh[i] = 0; lo[i] = 0; }
    __syncthreads();
    for (long long e = r0 + t; e < r1; e += 256) {
        int row = (e < E) ? dst0[e] : NI + dst1[e - E];
        atomicAdd(&lh[row >> 8], 1);
    }
    __syncthreads();
    for (int i = t; i < NBUK; i += 256)
        if (lh[i]) lb[i] = atomicAdd(&chead[i], lh[i]);
    __syncthreads();
    for (long long e = r0 + t; e < r1; e += 256) {
        int row, src;
        if (e < E) { row = dst0[e]; src = src0[e]; }
        else       { row = NI + dst1[e - E]; src = src1[e - E]; }
        int bin = row >> 8;
        int off = atomicAdd(&lo[bin], 1);
        ebuf[lb[bin] + off] = ((unsigned int)(row & 255) << 16) | (unsigned int)src;
    }
}

// ---------------------------------------------------------------------------
// Per-bucket fine counting sort in LDS -> rowptr + u16 eidx (coalesced out).
// ---------------------------------------------------------------------------
__global__ __launch_bounds__(256) void fsort_k(
    const int* __restrict__ crp, const unsigned int* __restrict__ ebuf,
    int* __restrict__ rowptr, u16* __restrict__ eidx, int NR)
{
    __shared__ unsigned int ep[EMAX];
    __shared__ u16 ss[EMAX];
    __shared__ int h[BUK], hd[BUK];
    int b = blockIdx.x, t = threadIdx.x;
    int base = crp[b];
    int n = crp[b + 1] - base;
    if (n > EMAX) n = EMAX;

    for (int i = t; i < n; i += 256) ep[i] = ebuf[base + i];
    if (t < BUK) h[t] = 0;
    __syncthreads();
    for (int i = t; i < n; i += 256) atomicAdd(&h[ep[i] >> 16], 1);
    __syncthreads();
    int v = (t < BUK) ? h[t] : 0;
    // inclusive scan over 256 bins (256 threads)
    for (int off = 1; off < 256; off <<= 1) {
        int x = (t >= off) ? h[t - off] : 0;
        __syncthreads();
        if (t < BUK) h[t] += x;
        __syncthreads();
    }
    int excl = (t < BUK) ? (h[t] - v) : 0;
    if (t < BUK) {
        int absrow = b * BUK + t;
        if (absrow < NR) rowptr[absrow] = base + excl;
        hd[t] = excl;
    }
    __syncthreads();
    for (int i = t; i < n; i += 256) {
        unsigned int p = ep[i];
        int pos = atomicAdd(&hd[p >> 16], 1);
        ss[pos] = (u16)(p & 0xffffu);
    }
    __syncthreads();
    for (int i = t; i < n; i += 256) eidx[base + i] = ss[i];
}

// ---------------------------------------------------------------------------
// Gather: S[r] = sum of bf16 feature rows. Wave per row, 4 edges in flight
// (16 lanes x dwordx4 per edge), fp32 acc, shfl-reduce, bf16 out.
// ---------------------------------------------------------------------------
__global__ __launch_bounds__(256) void gather_k(
    const int* __restrict__ rowptr, const u16* __restrict__ eidx,
    const u16* __restrict__ fu, const u16* __restrict__ fi,
    u16* __restrict__ S, int NI, int NR)
{
    int row = blockIdx.x * 4 + (threadIdx.x >> 6);
    int l = threadIdx.x & 63;
    if (row >= NR) return;
    const u16* F = (row < NI) ? fu : fi;
    int start = rowptr[row], end = rowptr[row + 1];
    int sub = l >> 4, li = l & 15;

    float a[8];
#pragma unroll
    for (int k = 0; k < 8; k++) a[k] = 0.f;

    for (int j = start; j < end; j += 4) {
        int je = j + sub;
        if (je < end) {
            int src = eidx[je];
            uint4 v = *(const uint4*)(F + (size_t)src * 128 + li * 8);
            unsigned int ww[4] = {v.x, v.y, v.z, v.w};
#pragma unroll
            for (int p = 0; p < 4; p++) {
                a[2 * p]     += bf2f((u16)(ww[p] & 0xffffu));
                a[2 * p + 1] += bf2f((u16)(ww[p] >> 16));
            }
        }
    }
#pragma unroll
    for (int k = 0; k < 8; k++) {
        a[k] += __shfl_xor(a[k], 16, 64);
        a[k] += __shfl_xor(a[k], 32, 64);
    }
    if (sub == 0) {
        uint4 o;
        o.x = ((unsigned int)f2bf(a[1]) << 16) | f2bf(a[0]);
        o.y = ((unsigned int)f2bf(a[3]) << 16) | f2bf(a[2]);
        o.z = ((unsigned int)f2bf(a[5]) << 16) | f2bf(a[4]);
        o.w = ((unsigned int)f2bf(a[7]) << 16) | f2bf(a[6]);
        *(uint4*)(S + (size_t)row * 128 + li * 8) = o;
    }
}

// ---------------------------------------------------------------------------
// h = relu(LN(msg + bmsg)*g + b) + feat  (msg bf16, feat fp32, out bf16)
// ---------------------------------------------------------------------------
__global__ __launch_bounds__(256) void ln_k(
    const u16* __restrict__ X, const float* __restrict__ bmsg,
    const float* __restrict__ feat, const float* __restrict__ g,
    const float* __restrict__ b, u16* __restrict__ H, int M)
{
    int row = blockIdx.x * 4 + (threadIdx.x >> 6);
    int lane = threadIdx.x & 63;
    if (row >= M) return;
    size_t base = (size_t)row * 128;
    float x0 = bf2f(X[base + lane])      + bmsg[lane];
    float x1 = bf2f(X[base + 64 + lane]) + bmsg[64 + lane];
    float s = x0 + x1;
#pragma unroll
    for (int o = 32; o > 0; o >>= 1) s += __shfl_xor(s, o, 64);
    float mean = s * 0.0078125f;
    float d0 = x0 - mean, d1 = x1 - mean;
    float q = d0 * d0 + d1 * d1;
#pragma unroll
    for (int o = 32; o > 0; o >>= 1) q += __shfl_xor(q, o, 64);
    float inv = rsqrtf(q * 0.0078125f + 1e-5f);
    float y0 = fmaxf(fmaf(d0 * inv, g[lane],      b[lane]),      0.f) + feat[base + lane];
    float y1 = fmaxf(fmaf(d1 * inv, g[64 + lane], b[64 + lane]), 0.f) + feat[base + 64 + lane];
    H[base + lane]      = f2bf(y0);
    H[base + 64 + lane] = f2bf(y1);
}

extern "C" void kernel_launch(void* const* d_in, const int* in_sizes, int n_in,
                              void* d_out, int out_size, void* d_ws, size_t ws_size,
                              hipStream_t stream)
{
    const float* feat_user   = (const float*)d_in[0];
    const float* feat_item   = (const float*)d_in[1];
    const float* W_u2i       = (const float*)d_in[2];
    const float* b_u2i       = (const float*)d_in[3];
    const float* W_i2u       = (const float*)d_in[4];
    const float* b_i2u       = (const float*)d_in[5];
    const float* self_w_user = (const float*)d_in[6];
    const float* self_w_item = (const float*)d_in[7];
    const float* ln_g_user   = (const float*)d_in[8];
    const float* ln_b_user   = (const float*)d_in[9];
    const float* ln_g_item   = (const float*)d_in[10];
    const float* ln_b_item   = (const float*)d_in[11];
    const float* ffn_w1      = (const float*)d_in[12];
    const float* ffn_b1      = (const float*)d_in[13];
    const float* ffn_w2      = (const float*)d_in[14];
    const float* ffn_b2      = (const float*)d_in[15];
    const int* src_u2i       = (const int*)d_in[16];
    const int* dst_u2i       = (const int*)d_in[17];
    const int* src_i2u       = (const int*)d_in[18];
    const int* dst_i2u       = (const int*)d_in[19];

    const int NU = in_sizes[0] / 128;
    const int NI = in_sizes[1] / 128;
    const int E  = in_sizes[16];
    const int NR = NI + NU;               // [0,NI)=item dst, [NI,NR)=user dst
    const int NBUK = (NR + BUK - 1) / BUK;

    // Workspace:
    //  R0: S_bf (gather out)  -> hid (FFN hidden)
    //  R1: featU_bf | featI_bf -> hU | hI (LN out)
    //  R2: CSR arrays (~8 MB) -> msgI | msgU (bf16)
    //  R3: transposed bf16 weights
    char* ws = (char*)d_ws;
    size_t R0sz = (size_t)NR * 128 * 2;
    size_t hidsz = (size_t)(NU > NI ? NU : NI) * 256 * 2;
    if (hidsz > R0sz) R0sz = hidsz;
    char* R0 = ws;
    char* R1 = R0 + R0sz;
    char* R2 = R1 + (size_t)NR * 128 * 2;
    char* R3 = R2 + (size_t)NR * 128 * 2;

    u16* Sb   = (u16*)R0;
    u16* hid  = (u16*)R0;
    u16* fub  = (u16*)R1;
    u16* fib  = fub + (size_t)NU * 128;
    u16* hU   = (u16*)R1;
    u16* hI   = hU + (size_t)NU * 128;
    u16* msgI = (u16*)R2;
    u16* msgU = msgI + (size_t)NI * 128;

    int* cnt    = (int*)R2;               // NBUK+1
    int* crp    = cnt + (NBUK + 1);       // NBUK+1
    int* chead  = crp + (NBUK + 1);       // NBUK
    int* rowptr = chead + NBUK;           // NR+1
    unsigned int* ebuf = (unsigned int*)(rowptr + NR + 1);  // 2E
    u16* eidx   = (u16*)(ebuf + 2 * (size_t)E);             // 2E

    u16* w_u2iT = (u16*)R3;
    u16* w_i2uT = w_u2iT + 16384;
    u16* selfUT = w_i2uT + 16384;
    u16* selfIT = selfUT + 16384;
    u16* ffn1T  = selfIT + 16384;   // [256][128]
    u16* ffn2T  = ffn1T + 32768;    // [128][256]

    float* out = (float*)d_out;
    dim3 blk(256);
    const int nu4 = NU * 128 / 4, ni4 = NI * 128 / 4;

    // --- prep: casts + weight transposes (fused) ---
    int prep_n = nu4 + ni4 + 131072;
    prep_k<<<dim3((prep_n + 255) / 256), blk, 0, stream>>>(
        feat_user, feat_item, fub, fib, nu4, ni4,
        W_u2i, W_i2u, self_w_user, self_w_item, ffn_w1, ffn_w2,
        w_u2iT, w_i2uT, selfUT, selfIT, ffn1T, ffn2T);

    // --- two-level counting sort -> CSR ---
    (void)hipMemsetAsync(cnt, 0, (size_t)(NBUK + 1) * 4, stream);
    chist_k<<<dim3(512), blk, 0, stream>>>(dst_u2i, dst_i2u, cnt, E, NI, NBUK);
    cscan_k<<<dim3(1), dim3(512), 0, stream>>>(cnt, crp, chead, rowptr, NBUK, NR);
    cpart_k<<<dim3(512), blk, 0, stream>>>(
        src_u2i, dst_u2i, src_i2u, dst_i2u, chead, ebuf, E, NI, NBUK);
    fsort_k<<<dim3(NBUK), blk, 0, stream>>>(crp, ebuf, rowptr, eidx, NR);

    // --- gather raw-feature sums (linearity of segment_sum) ---
    gather_k<<<dim3((NR + 3) / 4), blk, 0, stream>>>(rowptr, eidx, fub, fib, Sb, NI, NR);

    // --- msg = S @ W_rel^T + feat @ W_self^T (dual-GEMM, bf16 out) ---
    int gU = (NU + 127) / 128, gI = (NI + 127) / 128;
    mg_k<false, false, true><<<dim3(gI, 1), blk, 0, stream>>>(
        Sb, fib, w_u2iT, selfIT, 128, 128, 2, nullptr, nullptr, msgI, NI, 128);
    mg_k<false, false, true><<<dim3(gU, 1), blk, 0, stream>>>(
        Sb + (size_t)NI * 128, fub, w_i2uT, selfUT, 128, 128, 2, nullptr, nullptr, msgU, NU, 128);

    // --- LN -> ReLU -> residual ---
    ln_k<<<dim3((NU + 3) / 4), blk, 0, stream>>>(msgU, b_i2u, feat_user, ln_g_user, ln_b_user, hU, NU);
    ln_k<<<dim3((NI + 3) / 4), blk, 0, stream>>>(msgI, b_u2i, feat_item, ln_g_item, ln_b_item, hI, NI);

    // --- FFN user ---
    mg_k<true, true, true><<<dim3(gU, 2), blk, 0, stream>>>(
        hU, nullptr, ffn1T, nullptr, 128, 128, 1, ffn_b1, nullptr, hid, NU, 256);
    mg_k<false, true, false><<<dim3(gU, 1), blk, 0, stream>>>(
        hid, hid + 128, ffn2T, ffn2T + 128, 256, 256, 2, ffn_b2, out, nullptr, NU, 128);

    // --- FFN item ---
    mg_k<true, true, true><<<dim3(gI, 2), blk, 0, stream>>>(
        hI, nullptr, ffn1T, nullptr, 128, 128, 1, ffn_b1, nullptr, hid, NI, 256);
    mg_k<false, true, false><<<dim3(gI, 1), blk, 0, stream>>>(
        hid, hid + 128, ffn2T, ffn2T + 128, 256, 256, 2, ffn_b2,
        out + (size_t)NU * 128, nullptr, NI, 128);
}

// Round 7
// 337.033 us; speedup vs baseline: 4.4954x; 1.1555x over previous
//
#include <hip/hip_runtime.h>

typedef unsigned short u16;
typedef __attribute__((ext_vector_type(4))) float f32x4;
typedef __attribute__((ext_vector_type(8))) short bf16x8;

#define MAXB 512      // max coarse buckets one scan block supports
#define BUK  256      // dst rows per coarse bucket
#define EMAX 4096     // max edges per bucket (mean 3072, ~18 sigma headroom)

__device__ __forceinline__ float bf2f(u16 u) {
    union { unsigned int i; float f; } v; v.i = ((unsigned int)u) << 16; return v.f;
}
__device__ __forceinline__ u16 f2bf(float f) {
    union { float f; unsigned int i; } v; v.f = f;
    unsigned int r = v.i + 0x7fffu + ((v.i >> 16) & 1u);
    return (u16)(r >> 16);
}
__device__ __forceinline__ void gload16(const void* g, void* l) {
    __builtin_amdgcn_global_load_lds(
        (const __attribute__((address_space(1))) unsigned int*)g,
        (__attribute__((address_space(3))) unsigned int*)l, 16, 0, 0);
}

// ---------------------------------------------------------------------------
// Shared MFMA tile machinery: 256 thr = 4 waves, 128x128 C tile,
// wave = 64x64 (4x4 of v_mfma_f32_16x16x32_bf16), fp32 acc.
// ---------------------------------------------------------------------------
#define MFMA_PROLOG \
    __shared__ __align__(16) u16 As[128 * 128]; \
    __shared__ __align__(16) u16 Ws[128 * 128]; \
    const int tid = threadIdx.x, w = tid >> 6, l = tid & 63; \
    const int wr = (w >> 1) * 64, wc = (w & 1) * 64; \
    const int quad = l >> 4, lan = l & 15; \
    f32x4 acc[4][4]; \
    _Pragma("unroll") for (int i = 0; i < 4; i++) \
    _Pragma("unroll") for (int j = 0; j < 4; j++) acc[i][j] = (f32x4){0.f,0.f,0.f,0.f};

__device__ __forceinline__ void mfma_stage(
    const u16* Ab, int sA, const u16* Wb, int sW, int m0, int n0,
    int w, int l, u16* As, u16* Ws)
{
#pragma unroll
    for (int it = 0; it < 8; it++) {
        int o = ((it * 4 + w) * 64 + l) * 16;
        int row = o >> 8, cb = o & 255;
        gload16(Ab + (size_t)(m0 + row) * sA + (cb >> 1), (char*)As + o);
        gload16(Wb + (size_t)(n0 + row) * sW + (cb >> 1), (char*)Ws + o);
    }
}

#define MFMA_COMPUTE \
    _Pragma("unroll") for (int kk = 0; kk < 4; kk++) { \
        bf16x8 af[4], bfr[4]; \
        _Pragma("unroll") for (int i = 0; i < 4; i++) \
            af[i] = *(const bf16x8*)&As[(wr + i*16 + lan)*128 + kk*32 + quad*8]; \
        _Pragma("unroll") for (int j = 0; j < 4; j++) \
            bfr[j] = *(const bf16x8*)&Ws[(wc + j*16 + lan)*128 + kk*32 + quad*8]; \
        _Pragma("unroll") for (int i = 0; i < 4; i++) \
        _Pragma("unroll") for (int j = 0; j < 4; j++) \
            acc[i][j] = __builtin_amdgcn_mfma_f32_16x16x32_bf16(af[i], bfr[j], acc[i][j], 0,0,0); \
    }

// ---------------------------------------------------------------------------
// msg = S @ Wrel^T + fb @ Wself^T over padded concat rows; weights selected
// per block by section (m0 < NUp -> user). bf16 out.
// ---------------------------------------------------------------------------
__global__ __launch_bounds__(256) void msg_k(
    const u16* __restrict__ S, const u16* __restrict__ fb,
    const u16* __restrict__ wUrel, const u16* __restrict__ wUself,
    const u16* __restrict__ wIrel, const u16* __restrict__ wIself,
    int NUp, u16* __restrict__ C)
{
    MFMA_PROLOG
    const int m0 = blockIdx.x * 128;
    const bool isU = m0 < NUp;
    const u16* W0 = isU ? wUrel : wIrel;
    const u16* W1 = isU ? wUself : wIself;

    mfma_stage(S, 128, W0, 128, m0, 0, w, l, As, Ws);
    __syncthreads();
    MFMA_COMPUTE
    __syncthreads();
    mfma_stage(fb, 128, W1, 128, m0, 0, w, l, As, Ws);
    __syncthreads();
    MFMA_COMPUTE

#pragma unroll
    for (int j = 0; j < 4; j++) {
        int col = wc + j * 16 + lan;
#pragma unroll
        for (int i = 0; i < 4; i++) {
            int row0 = m0 + wr + i * 16 + quad * 4;
#pragma unroll
            for (int r = 0; r < 4; r++)
                C[(size_t)(row0 + r) * 128 + col] = f2bf(acc[i][j][r]);
        }
    }
}

// ---------------------------------------------------------------------------
// FFN1: hid = relu(h @ ffn1T^T + b1), N=256 (grid.y col tiles), bf16 out.
// ---------------------------------------------------------------------------
__global__ __launch_bounds__(256) void ffn1_k(
    const u16* __restrict__ h, const u16* __restrict__ W,
    const float* __restrict__ bias, u16* __restrict__ C)
{
    MFMA_PROLOG
    const int m0 = blockIdx.x * 128, n0 = blockIdx.y * 128;
    mfma_stage(h, 128, W, 128, m0, n0, w, l, As, Ws);
    __syncthreads();
    MFMA_COMPUTE

#pragma unroll
    for (int j = 0; j < 4; j++) {
        int col = n0 + wc + j * 16 + lan;
        float bb = bias[col];
#pragma unroll
        for (int i = 0; i < 4; i++) {
            int row0 = m0 + wr + i * 16 + quad * 4;
#pragma unroll
            for (int r = 0; r < 4; r++)
                C[(size_t)(row0 + r) * 256 + col] = f2bf(fmaxf(acc[i][j][r] + bb, 0.f));
        }
    }
}

// ---------------------------------------------------------------------------
// FFN2: out = hid @ ffn2T^T + b2 (K=256 via 2 chunks), fp32 out with
// pad-row skip + section remap to the unpadded output layout.
// ---------------------------------------------------------------------------
__global__ __launch_bounds__(256) void ffn2_k(
    const u16* __restrict__ hid, const u16* __restrict__ W,
    const float* __restrict__ bias, float* __restrict__ out,
    int NU, int NUp, int NI)
{
    MFMA_PROLOG
    const int m0 = blockIdx.x * 128;
    mfma_stage(hid, 256, W, 256, m0, 0, w, l, As, Ws);
    __syncthreads();
    MFMA_COMPUTE
    __syncthreads();
    mfma_stage(hid + 128, 256, W + 128, 256, m0, 0, w, l, As, Ws);
    __syncthreads();
    MFMA_COMPUTE

#pragma unroll
    for (int j = 0; j < 4; j++) {
        int col = wc + j * 16 + lan;
        float bb = bias[col];
#pragma unroll
        for (int i = 0; i < 4; i++) {
            int row0 = m0 + wr + i * 16 + quad * 4;
#pragma unroll
            for (int r = 0; r < 4; r++) {
                int gr = row0 + r, orow;
                if (gr < NUp) { if (gr >= NU) continue; orow = gr; }
                else { int ir = gr - NUp; if (ir >= NI) continue; orow = NU + ir; }
                out[(size_t)orow * 128 + col] = acc[i][j][r] + bb;
            }
        }
    }
}

// ---------------------------------------------------------------------------
// prep: feature casts (user-first padded layout) + 6 weight transposes +
// cnt zeroing + pad-row zeroing of S and fb.
// ---------------------------------------------------------------------------
__global__ __launch_bounds__(256) void prep_k(
    const float* __restrict__ fu, const float* __restrict__ fi,
    u16* __restrict__ fb, u16* __restrict__ S,
    int nu4, int ni4, int NU, int NUp, int NI, int NIp,
    const float* __restrict__ w0, const float* __restrict__ w1,
    const float* __restrict__ w2, const float* __restrict__ w3,
    const float* __restrict__ w4, const float* __restrict__ w5,
    u16* __restrict__ o0, u16* __restrict__ o1, u16* __restrict__ o2,
    u16* __restrict__ o3, u16* __restrict__ o4, u16* __restrict__ o5,
    int* __restrict__ cnt, int NBUK)
{
    int t = blockIdx.x * 256 + threadIdx.x;
    int nc = nu4 + ni4;
    if (t < nc) {
        const float* X; u16* Y; int idx;
        if (t < nu4) { X = fu; Y = fb; idx = t; }
        else { X = fi; Y = fb + (size_t)NUp * 128; idx = t - nu4; }
        float4 v = ((const float4*)X)[idx];
        ((ushort4*)Y)[idx] = make_ushort4(f2bf(v.x), f2bf(v.y), f2bf(v.z), f2bf(v.w));
        return;
    }
    int u = t - nc;
    if (u < 131072) {
        const float* W; u16* O; int K, N, idx;
        if (u < 65536) {
            int s = u >> 14; idx = u & 16383; K = 128; N = 128;
            W = s == 0 ? w0 : s == 1 ? w1 : s == 2 ? w2 : w3;
            O = s == 0 ? o0 : s == 1 ? o1 : s == 2 ? o2 : o3;
        } else {
            int v2 = u - 65536; int s = v2 >> 15; idx = v2 & 32767;
            if (s == 0) { W = w4; O = o4; K = 128; N = 256; }
            else        { W = w5; O = o5; K = 256; N = 128; }
        }
        int k = idx / N, n = idx % N;
        O[n * K + k] = f2bf(W[idx]);
        return;
    }
    int u2 = u - 131072;
    int padrows = (NUp - NU) + (NIp - NI);
    int padw = padrows * 32;           // ushort4 per array
    if (u2 < 2 * padw) {
        int arr = u2 / padw, k = u2 % padw;
        int prow = k >> 5, c4 = k & 31;
        int row = (prow < NUp - NU) ? (NU + prow) : (NUp + NI + (prow - (NUp - NU)));
        u16* B = arr ? fb : S;
        ((ushort4*)B)[(size_t)row * 32 + c4] = make_ushort4(0, 0, 0, 0);
        return;
    }
    int c = u2 - 2 * padw;
    if (c <= NBUK) cnt[c] = 0;
}

// ---------------------------------------------------------------------------
// CSR build: coarse histogram -> scan -> partition -> per-bucket LDS sort.
// CSR row space is item-first: [0,NI)=item dst, [NI,NR)=user dst.
// ---------------------------------------------------------------------------
__global__ __launch_bounds__(256) void chist_k(
    const int* __restrict__ dst0, const int* __restrict__ dst1,
    int* __restrict__ cnt, int E, int NI, int NBUK)
{
    __shared__ int lh[MAXB];
    int t = threadIdx.x;
    for (int i = t; i < MAXB; i += 256) lh[i] = 0;
    __syncthreads();
    for (long long e = (long long)blockIdx.x * 256 + t; e < 2LL * E;
         e += (long long)gridDim.x * 256) {
        int row = (e < E) ? dst0[e] : NI + dst1[e - E];
        atomicAdd(&lh[row >> 8], 1);
    }
    __syncthreads();
    for (int i = t; i < NBUK; i += 256)
        if (lh[i]) atomicAdd(&cnt[i], lh[i]);
}

__global__ __launch_bounds__(512) void cscan_k(
    const int* __restrict__ cnt, int* __restrict__ crp, int* __restrict__ chead,
    int* __restrict__ rowptr, int NBUK, int NR)
{
    __shared__ int s[512];
    int t = threadIdx.x;
    int carry = 0;
    for (int base = 0; base < NBUK; base += 512) {
        int i = base + t;
        int v = (i < NBUK) ? cnt[i] : 0;
        s[t] = v;
        __syncthreads();
        for (int off = 1; off < 512; off <<= 1) {
            int x = (t >= off) ? s[t - off] : 0;
            __syncthreads();
            s[t] += x;
            __syncthreads();
        }
        int excl = s[t] - v + carry;
        if (i < NBUK) { crp[i] = excl; chead[i] = excl; }
        carry += s[511];
        __syncthreads();
    }
    if (t == 0) { crp[NBUK] = carry; rowptr[NR] = carry; }
}

__global__ __launch_bounds__(256) void cpart_k(
    const int* __restrict__ src0, const int* __restrict__ dst0,
    const int* __restrict__ src1, const int* __restrict__ dst1,
    int* __restrict__ chead, unsigned int* __restrict__ ebuf,
    int E, int NI, int NBUK)
{
    __shared__ int lh[MAXB], lb[MAXB], lo[MAXB];
    int t = threadIdx.x;
    long long total = 2LL * E;
    long long per = (total + gridDim.x - 1) / gridDim.x;
    long long r0 = (long long)blockIdx.x * per;
    long long r1 = r0 + per; if (r1 > total) r1 = total;

    for (int i = t; i < MAXB; i += 256) { lh[i] = 0; lo[i] = 0; }
    __syncthreads();
    for (long long e = r0 + t; e < r1; e += 256) {
        int row = (e < E) ? dst0[e] : NI + dst1[e - E];
        atomicAdd(&lh[row >> 8], 1);
    }
    __syncthreads();
    for (int i = t; i < NBUK; i += 256)
        if (lh[i]) lb[i] = atomicAdd(&chead[i], lh[i]);
    __syncthreads();
    for (long long e = r0 + t; e < r1; e += 256) {
        int row, src;
        if (e < E) { row = dst0[e]; src = src0[e]; }
        else       { row = NI + dst1[e - E]; src = src1[e - E]; }
        int bin = row >> 8;
        int off = atomicAdd(&lo[bin], 1);
        ebuf[lb[bin] + off] = ((unsigned int)(row & 255) << 16) | (unsigned int)src;
    }
}

__global__ __launch_bounds__(256) void fsort_k(
    const int* __restrict__ crp, const unsigned int* __restrict__ ebuf,
    int* __restrict__ rowptr, u16* __restrict__ eidx, int NR)
{
    __shared__ unsigned int ep[EMAX];
    __shared__ u16 ss[EMAX];
    __shared__ int h[BUK], hd[BUK];
    int b = blockIdx.x, t = threadIdx.x;
    int base = crp[b];
    int n = crp[b + 1] - base;
    if (n > EMAX) n = EMAX;

    for (int i = t; i < n; i += 256) ep[i] = ebuf[base + i];
    if (t < BUK) h[t] = 0;
    __syncthreads();
    for (int i = t; i < n; i += 256) atomicAdd(&h[ep[i] >> 16], 1);
    __syncthreads();
    int v = (t < BUK) ? h[t] : 0;
    for (int off = 1; off < 256; off <<= 1) {
        int x = (t >= off) ? h[t - off] : 0;
        __syncthreads();
        if (t < BUK) h[t] += x;
        __syncthreads();
    }
    int excl = (t < BUK) ? (h[t] - v) : 0;
    if (t < BUK) {
        int absrow = b * BUK + t;
        if (absrow < NR) rowptr[absrow] = base + excl;
        hd[t] = excl;
    }
    __syncthreads();
    for (int i = t; i < n; i += 256) {
        unsigned int p = ep[i];
        int pos = atomicAdd(&hd[p >> 16], 1);
        ss[pos] = (u16)(p & 0xffffu);
    }
    __syncthreads();
    for (int i = t; i < n; i += 256) eidx[base + i] = ss[i];
}

// ---------------------------------------------------------------------------
// Gather: wave per csr row, 8 edges in flight (2x unroll, 16 lanes x uint4),
// fp32 acc, shfl-reduce, bf16 out to padded user-first S.
// ---------------------------------------------------------------------------
__global__ __launch_bounds__(256) void gather_k(
    const int* __restrict__ rowptr, const u16* __restrict__ eidx,
    const u16* __restrict__ fb, u16* __restrict__ S,
    int NI, int NR, int NUp)
{
    int row = blockIdx.x * 4 + (threadIdx.x >> 6);
    int l = threadIdx.x & 63;
    if (row >= NR) return;
    // item-dst rows gather USER features; user-dst rows gather ITEM features
    const u16* F = (row < NI) ? fb : fb + (size_t)NUp * 128;
    int srow = (row < NI) ? (NUp + row) : (row - NI);
    int start = rowptr[row], end = rowptr[row + 1];
    int sub = l >> 4, li = l & 15;

    float a[8];
#pragma unroll
    for (int k = 0; k < 8; k++) a[k] = 0.f;

    for (int j = start; j < end; j += 8) {
        int je0 = j + sub, je1 = j + 4 + sub;
        int c0 = je0 < end ? je0 : end - 1;
        int c1 = je1 < end ? je1 : end - 1;
        int s0 = eidx[c0], s1 = eidx[c1];
        uint4 v0 = *(const uint4*)(F + (size_t)s0 * 128 + li * 8);
        uint4 v1 = *(const uint4*)(F + (size_t)s1 * 128 + li * 8);
        unsigned int w0[4] = {v0.x, v0.y, v0.z, v0.w};
        unsigned int w1[4] = {v1.x, v1.y, v1.z, v1.w};
        if (je0 < end) {
#pragma unroll
            for (int p = 0; p < 4; p++) {
                a[2*p]   += bf2f((u16)(w0[p] & 0xffffu));
                a[2*p+1] += bf2f((u16)(w0[p] >> 16));
            }
        }
        if (je1 < end) {
#pragma unroll
            for (int p = 0; p < 4; p++) {
                a[2*p]   += bf2f((u16)(w1[p] & 0xffffu));
                a[2*p+1] += bf2f((u16)(w1[p] >> 16));
            }
        }
    }
#pragma unroll
    for (int k = 0; k < 8; k++) {
        a[k] += __shfl_xor(a[k], 16, 64);
        a[k] += __shfl_xor(a[k], 32, 64);
    }
    if (sub == 0) {
        uint4 o;
        o.x = ((unsigned int)f2bf(a[1]) << 16) | f2bf(a[0]);
        o.y = ((unsigned int)f2bf(a[3]) << 16) | f2bf(a[2]);
        o.z = ((unsigned int)f2bf(a[5]) << 16) | f2bf(a[4]);
        o.w = ((unsigned int)f2bf(a[7]) << 16) | f2bf(a[6]);
        *(uint4*)(S + (size_t)srow * 128 + li * 8) = o;
    }
}

// ---------------------------------------------------------------------------
// Fused two-side LN: h = relu(LN(msg + bmsg)*g + b) + fb, in-place over fb.
// ---------------------------------------------------------------------------
__global__ __launch_bounds__(256) void lnf_k(
    const u16* __restrict__ msg, u16* __restrict__ fb,
    const float* __restrict__ bmU, const float* __restrict__ bmI,
    const float* __restrict__ gU, const float* __restrict__ bU,
    const float* __restrict__ gI, const float* __restrict__ bI,
    int NUp, int NRp)
{
    int row = blockIdx.x * 4 + (threadIdx.x >> 6);
    int lane = threadIdx.x & 63;
    if (row >= NRp) return;
    bool isU = row < NUp;
    const float* bm = isU ? bmU : bmI;
    const float* g  = isU ? gU : gI;
    const float* b  = isU ? bU : bI;
    size_t base = (size_t)row * 128;
    float x0 = bf2f(msg[base + lane])      + bm[lane];
    float x1 = bf2f(msg[base + 64 + lane]) + bm[64 + lane];
    float s = x0 + x1;
#pragma unroll
    for (int o = 32; o > 0; o >>= 1) s += __shfl_xor(s, o, 64);
    float mean = s * 0.0078125f;
    float d0 = x0 - mean, d1 = x1 - mean;
    float q = d0 * d0 + d1 * d1;
#pragma unroll
    for (int o = 32; o > 0; o >>= 1) q += __shfl_xor(q, o, 64);
    float inv = rsqrtf(q * 0.0078125f + 1e-5f);
    float y0 = fmaxf(fmaf(d0 * inv, g[lane],      b[lane]),      0.f) + bf2f(fb[base + lane]);
    float y1 = fmaxf(fmaf(d1 * inv, g[64 + lane], b[64 + lane]), 0.f) + bf2f(fb[base + 64 + lane]);
    fb[base + lane]      = f2bf(y0);
    fb[base + 64 + lane] = f2bf(y1);
}

extern "C" void kernel_launch(void* const* d_in, const int* in_sizes, int n_in,
                              void* d_out, int out_size, void* d_ws, size_t ws_size,
                              hipStream_t stream)
{
    const float* feat_user   = (const float*)d_in[0];
    const float* feat_item   = (const float*)d_in[1];
    const float* W_u2i       = (const float*)d_in[2];
    const float* b_u2i       = (const float*)d_in[3];
    const float* W_i2u       = (const float*)d_in[4];
    const float* b_i2u       = (const float*)d_in[5];
    const float* self_w_user = (const float*)d_in[6];
    const float* self_w_item = (const float*)d_in[7];
    const float* ln_g_user   = (const float*)d_in[8];
    const float* ln_b_user   = (const float*)d_in[9];
    const float* ln_g_item   = (const float*)d_in[10];
    const float* ln_b_item   = (const float*)d_in[11];
    const float* ffn_w1      = (const float*)d_in[12];
    const float* ffn_b1      = (const float*)d_in[13];
    const float* ffn_w2      = (const float*)d_in[14];
    const float* ffn_b2      = (const float*)d_in[15];
    const int* src_u2i       = (const int*)d_in[16];
    const int* dst_u2i       = (const int*)d_in[17];
    const int* src_i2u       = (const int*)d_in[18];
    const int* dst_i2u       = (const int*)d_in[19];

    const int NU = in_sizes[0] / 128;
    const int NI = in_sizes[1] / 128;
    const int E  = in_sizes[16];
    const int NR = NI + NU;                    // CSR rows, item-first
    const int NUp = (NU + 127) & ~127;
    const int NIp = (NI + 127) & ~127;
    const int NRp = NUp + NIp;                 // padded concat rows, user-first
    const int NBUK = (NR + BUK - 1) / BUK;

    // Workspace (~90 MB):
    //  S [NRp*256B]  | msg [NRp*256B]   -> together reused as hid [NRp*512B]
    //  fb [NRp*256B] (bf16 features -> h in-place)
    //  CSR arrays (~13 MB) | transposed weights (0.26 MB)
    char* ws = (char*)d_ws;
    u16* S    = (u16*)ws;
    u16* msg  = S + (size_t)NRp * 128;
    u16* hid  = S;                              // NRp x 256, overlays S|msg
    u16* fb   = msg + (size_t)NRp * 128;
    char* R2  = (char*)(fb + (size_t)NRp * 128);

    int* cnt    = (int*)R2;                     // NBUK+1
    int* crp    = cnt + (NBUK + 1);             // NBUK+1
    int* chead  = crp + (NBUK + 1);             // NBUK
    int* rowptr = chead + NBUK;                 // NR+1
    unsigned int* ebuf = (unsigned int*)(rowptr + NR + 1);   // 2E
    u16* eidx   = (u16*)(ebuf + 2 * (size_t)E);              // 2E
    u16* wts    = (u16*)(eidx + 2 * (size_t)E);
    u16* w_u2iT = wts;
    u16* w_i2uT = w_u2iT + 16384;
    u16* selfUT = w_i2uT + 16384;
    u16* selfIT = selfUT + 16384;
    u16* ffn1T  = selfIT + 16384;   // [256][128]
    u16* ffn2T  = ffn1T + 32768;    // [128][256]

    float* out = (float*)d_out;
    dim3 blk(256);
    const int nu4 = NU * 128 / 4, ni4 = NI * 128 / 4;
    const int padw = ((NUp - NU) + (NIp - NI)) * 32;
    const int prep_n = nu4 + ni4 + 131072 + 2 * padw + NBUK + 1;

    // 1. prep: casts + weight transposes + cnt zero + pad zero
    prep_k<<<dim3((prep_n + 255) / 256), blk, 0, stream>>>(
        feat_user, feat_item, fb, S, nu4, ni4, NU, NUp, NI, NIp,
        W_u2i, W_i2u, self_w_user, self_w_item, ffn_w1, ffn_w2,
        w_u2iT, w_i2uT, selfUT, selfIT, ffn1T, ffn2T, cnt, NBUK);

    // 2-5. CSR build (two-level counting sort by dst)
    chist_k<<<dim3(512), blk, 0, stream>>>(dst_u2i, dst_i2u, cnt, E, NI, NBUK);
    cscan_k<<<dim3(1), dim3(512), 0, stream>>>(cnt, crp, chead, rowptr, NBUK, NR);
    cpart_k<<<dim3(512), blk, 0, stream>>>(
        src_u2i, dst_u2i, src_i2u, dst_i2u, chead, ebuf, E, NI, NBUK);
    fsort_k<<<dim3(NBUK), blk, 0, stream>>>(crp, ebuf, rowptr, eidx, NR);

    // 6. gather raw-feature sums -> S (padded user-first)
    gather_k<<<dim3((NR + 3) / 4), blk, 0, stream>>>(
        rowptr, eidx, fb, S, NI, NR, NUp);

    // 7. msg = S @ Wrel^T + fb @ Wself^T (both sides, one dispatch)
    msg_k<<<dim3(NRp / 128), blk, 0, stream>>>(
        S, fb, w_i2uT, selfUT, w_u2iT, selfIT, NUp, msg);

    // 8. LN -> ReLU -> residual (both sides), h in-place over fb
    lnf_k<<<dim3((NRp + 3) / 4), blk, 0, stream>>>(
        msg, fb, b_i2u, b_u2i, ln_g_user, ln_b_user, ln_g_item, ln_b_item,
        NUp, NRp);

    // 9. FFN1: hid = relu(h @ W1 + b1)   (S|msg regions now dead -> hid)
    ffn1_k<<<dim3(NRp / 128, 2), blk, 0, stream>>>(fb, ffn1T, ffn_b1, hid);

    // 10. FFN2: out = hid @ W2 + b2 (fp32, pad-skip remap)
    ffn2_k<<<dim3(NRp / 128), blk, 0, stream>>>(
        hid, ffn2T, ffn_b2, out, NU, NUp, NI);
}